// Round 11
// baseline (3981.818 us; speedup 1.0000x reference)
//
#include <hip/hip_runtime.h>
#include <stdint.h>

#define DEV __device__ __forceinline__

constexpr int E_ = 16, M_ = 128, H_ = 2048, I_ = 2048;
constexpr int X_ = 16;            // A*B = 2*8
constexpr int N1 = 2 * I_;        // 4096
constexpr int ROWS = X_ * M_;     // 2048 rows per expert

typedef short bfrag __attribute__((ext_vector_type(8)));   // 8 bf16 (4 VGPRs)
typedef float ffrag __attribute__((ext_vector_type(4)));   // MFMA C/D frag
typedef unsigned short us8 __attribute__((ext_vector_type(8)));

DEV unsigned short f2bf(float f) {
    union { float f; unsigned u; } v; v.f = f;
    unsigned u = v.u;
    u += 0x7fffu + ((u >> 16) & 1u);   // RNE
    return (unsigned short)(u >> 16);
}

DEV void gload16(const void* g, void* lds_wave_base) {
    __builtin_amdgcn_global_load_lds(
        (const __attribute__((address_space(1))) unsigned int*)g,
        (__attribute__((address_space(3))) unsigned int*)lds_wave_base,
        16, 0, 0);
}

DEV void block_bar() {
    asm volatile("" ::: "memory");
    __builtin_amdgcn_s_barrier();
    asm volatile("" ::: "memory");
}

// ---------------- converts ----------------

// dispatched (X,E,M,H) f32 -> a_bf (E, X*M, H) bf16  (token-major per expert)
__global__ __launch_bounds__(256) void convert_a(const float* __restrict__ in,
                                                 unsigned short* __restrict__ outb) {
    const int n4 = X_ * E_ * M_ * H_ / 4;
    int idx = blockIdx.x * 256 + threadIdx.x;
    int stride = gridDim.x * 256;
    for (int f = idx; f < n4; f += stride) {
        float4 v = ((const float4*)in)[f];
        ushort4 o;
        o.x = f2bf(v.x); o.y = f2bf(v.y); o.z = f2bf(v.z); o.w = f2bf(v.w);
        const int c = f & 511;          // float4 within row (H/4 = 512)
        const int row = f >> 9;         // (x,e,m) row
        const int m = row & 127, e = (row >> 7) & 15, x = row >> 11;
        ((ushort4*)outb)[((size_t)(e * ROWS + x * M_ + m) << 9) + c] = o;
    }
}

// gate_up (E,H,4096) fp32 -> b1t (E,4096,H) bf16, de-interleaved
__global__ __launch_bounds__(256) void convert_b1(const float* __restrict__ gup,
                                                  unsigned short* __restrict__ b1t) {
    const int e = blockIdx.x, h0 = blockIdx.y * 64, n0 = blockIdx.z * 128;
    __shared__ float tile[64][129];
    const float* src = gup + (size_t)e * H_ * N1;
    const int t = threadIdx.x;
#pragma unroll
    for (int i = 0; i < 8; ++i) {
        int idx = i * 1024 + t * 4;
        int r = idx >> 7, c = idx & 127;
        float4 v = *(const float4*)(src + (size_t)(h0 + r) * N1 + n0 + c);
        tile[r][c] = v.x; tile[r][c + 1] = v.y; tile[r][c + 2] = v.z; tile[r][c + 3] = v.w;
    }
    __syncthreads();
    const int p = t >> 2;
    const int hh = (t & 3) * 16;
    us8 g0, g1, u0, u1;
#pragma unroll
    for (int k = 0; k < 8; ++k) {
        g0[k] = f2bf(tile[hh + k][2 * p]);
        u0[k] = f2bf(tile[hh + k][2 * p + 1]);
        g1[k] = f2bf(tile[hh + 8 + k][2 * p]);
        u1[k] = f2bf(tile[hh + 8 + k][2 * p + 1]);
    }
    unsigned short* dg = b1t + ((size_t)e * N1 + (n0 >> 1) + p) * H_ + h0 + hh;
    unsigned short* du = b1t + ((size_t)e * N1 + I_ + (n0 >> 1) + p) * H_ + h0 + hh;
    *(us8*)dg = g0; *(us8*)(dg + 8) = g1;
    *(us8*)du = u0; *(us8*)(du + 8) = u1;
}

// down (E,I,H) fp32 -> b2t (E,H,I) bf16
__global__ __launch_bounds__(256) void convert_b2(const float* __restrict__ dwn,
                                                  unsigned short* __restrict__ b2t) {
    const int e = blockIdx.x, i0 = blockIdx.y * 64, h0 = blockIdx.z * 64;
    __shared__ float tile[64][65];
    const float* src = dwn + (size_t)e * I_ * H_;
    const int t = threadIdx.x;
#pragma unroll
    for (int it = 0; it < 4; ++it) {
        int idx = it * 1024 + t * 4;
        int r = idx >> 6, c = idx & 63;
        float4 v = *(const float4*)(src + (size_t)(i0 + r) * H_ + h0 + c);
        tile[r][c] = v.x; tile[r][c + 1] = v.y; tile[r][c + 2] = v.z; tile[r][c + 3] = v.w;
    }
    __syncthreads();
    const int hl = t >> 2, ii = (t & 3) * 16;
    us8 o0, o1;
#pragma unroll
    for (int k = 0; k < 8; ++k) {
        o0[k] = f2bf(tile[ii + k][hl]);
        o1[k] = f2bf(tile[ii + 8 + k][hl]);
    }
    unsigned short* d = b2t + ((size_t)e * H_ + h0 + hl) * I_ + i0 + ii;
    *(us8*)d = o0; *(us8*)(d + 8) = o1;
}

// ---- 256x256 8-wave, BK=64, 2-buf, free-run + PARITY-STAGGERED GEMM ----
// MODE 0: gemm1 (gate_up + GLU epilogue); MODE 1: gemm2 (down proj + bias).
//
// Base = round-6 structure (513us, 48% MfmaUtil): 1 barrier/tile, counted
// lgkm, stage 1 tile ahead. Round-6 limiter (from counters): LDS pipe
// (~2760 cyc/tile) and MFMA pipe (~2483 cyc/tile) only overlapped ~430 cyc
// because waves converge at the barrier and move quasi-lockstep (all read,
// then all MFMA). Fix: WAVE-PARITY STAGGER — odd waves process A-half1
// first, even waves A-half0 first (and B halves mirrored), so at any
// instant ~half the waves feed the MFMA pipe while the other half issue
// LDS reads. Same reads, same MFMA count, same accumulators; wave-uniform
// branch with NO barriers inside (tile-top barrier is shared) -> safe.
template <int MODE>
__global__ __launch_bounds__(512, 2) void gemm8p(
    const unsigned short* __restrict__ A,   // (E,2048,2048) bf16
    const unsigned short* __restrict__ B,   // MODE0: (E,4096,2048); MODE1: (E,2048,2048)
    const float* __restrict__ bias,         // MODE0: (E,4096) interleaved; MODE1: (E,2048)
    void* __restrict__ outv)                // MODE0: act bf16 (E,2048,2048); MODE1: f32 (2048,16,2048)
{
    constexpr int LD = 2048;
    constexpr int NT = 2048 / 64;           // 32 K-tiles

    __shared__ unsigned short lds[2][2][256 * 64];   // [buf][A/B][row*64+k]

    const int t = threadIdx.x, wave = t >> 6, lane = t & 63;
    const int wr = wave >> 2, wc = wave & 3;         // 2M x 4N

    // XCD-aware bijective swizzle (nwg % 8 == 0 for both modes)
    int id = blockIdx.x;
    const int cpx = gridDim.x >> 3;
    id = (id & 7) * cpx + (id >> 3);
    int e, mt, bt;
    if (MODE == 0) { e = id >> 7; mt = (id >> 4) & 7; bt = id & 15; }
    else           { e = id >> 6; mt = (id >> 3) & 7; bt = id & 7; }

    const unsigned short* Aexp = A + ((size_t)e * ROWS + mt * 256) * LD;
    const unsigned short* Bexp = (MODE == 0)
        ? B + (size_t)e * N1 * LD
        : B + ((size_t)e * H_ + bt * 256) * LD;

    ffrag acc[8][4];
#pragma unroll
    for (int i = 0; i < 8; ++i)
#pragma unroll
        for (int j = 0; j < 4; ++j) acc[i][j] = ffrag{0.f, 0.f, 0.f, 0.f};

    const int rsub = lane >> 3;
    const int csw = ((lane & 7) ^ (lane >> 3)) * 8;  // inverse-swizzled k-chunk (elements)

    auto stage = [&](int kt, int b) {
        const int k0 = kt * 64;
#pragma unroll
        for (int i = 0; i < 4; ++i) {
            const int Rb = (wave * 4 + i) * 8;
            const int r = Rb + rsub;
            gload16(Aexp + (size_t)r * LD + k0 + csw, (void*)&lds[b][0][Rb * 64]);
        }
#pragma unroll
        for (int i = 0; i < 4; ++i) {
            const int Rb = (wave * 4 + i) * 8;
            const int r = Rb + rsub;
            int grow;
            if (MODE == 0)
                grow = ((r >> 5) & 1) * I_ + bt * 128 + (r >> 6) * 32 + (r & 31);
            else
                grow = r;
            gload16(Bexp + (size_t)grow * LD + k0 + csw, (void*)&lds[b][1][Rb * 64]);
        }
    };

    stage(0, 0);

    const int l15 = lane & 15, lr16 = lane >> 4, sw = lane & 7;
    const int arow0 = wr * 128 + l15;       // A row base for this wave/lane
    const int brow0 = wc * 64 + l15;        // B row base

#pragma unroll 2
    for (int kt = 0; kt < NT; ++kt) {
        const int cur = kt & 1;

        // drain this tile's stage loads (issued one tile ago -> ~free)
        asm volatile("s_waitcnt vmcnt(0)" ::: "memory");
        __builtin_amdgcn_sched_barrier(0);
        block_bar();   // publish buf[cur]; old buffer's reads all retired

        bfrag bB0[2][2], bB1[2][2];

        if ((wave & 1) == 0) {
            // ======== EVEN waves: A-half0 first ========
            bfrag af[4][2];
            // issue: bB0 (4), af = A-half0 (8), bB1 (4)
#pragma unroll
            for (int nf = 0; nf < 2; ++nf)
#pragma unroll
                for (int ks = 0; ks < 2; ++ks)
                    bB0[nf][ks] = *(const bfrag*)&lds[cur][1][(brow0 + nf * 16) * 64 + (((ks * 4 + lr16) ^ sw) * 8)];
#pragma unroll
            for (int mf = 0; mf < 4; ++mf)
#pragma unroll
                for (int ks = 0; ks < 2; ++ks)
                    af[mf][ks] = *(const bfrag*)&lds[cur][0][(arow0 + mf * 16) * 64 + (((ks * 4 + lr16) ^ sw) * 8)];
            asm volatile("" ::: "memory");
#pragma unroll
            for (int nf = 0; nf < 2; ++nf)
#pragma unroll
                for (int ks = 0; ks < 2; ++ks)
                    bB1[nf][ks] = *(const bfrag*)&lds[cur][1][(brow0 + 32 + nf * 16) * 64 + (((ks * 4 + lr16) ^ sw) * 8)];

            if (kt + 1 < NT) stage(kt + 1, cur ^ 1);

            // blk0 (mh0,nh0)
            asm volatile("s_waitcnt lgkmcnt(4)" ::: "memory");
            __builtin_amdgcn_sched_barrier(0);
            __builtin_amdgcn_s_setprio(1);
#pragma unroll
            for (int mf = 0; mf < 4; ++mf)
#pragma unroll
                for (int nf = 0; nf < 2; ++nf)
#pragma unroll
                    for (int ks = 0; ks < 2; ++ks)
                        acc[mf][nf] = __builtin_amdgcn_mfma_f32_16x16x32_bf16(
                            af[mf][ks], bB0[nf][ks], acc[mf][nf], 0, 0, 0);
            __builtin_amdgcn_s_setprio(0);

            // blk1 (mh0,nh1)
            asm volatile("s_waitcnt lgkmcnt(0)" ::: "memory");
            __builtin_amdgcn_sched_barrier(0);
            __builtin_amdgcn_s_setprio(1);
#pragma unroll
            for (int mf = 0; mf < 4; ++mf)
#pragma unroll
                for (int nf = 0; nf < 2; ++nf)
#pragma unroll
                    for (int ks = 0; ks < 2; ++ks)
                        acc[mf][2 + nf] = __builtin_amdgcn_mfma_f32_16x16x32_bf16(
                            af[mf][ks], bB1[nf][ks], acc[mf][2 + nf], 0, 0, 0);
            __builtin_amdgcn_s_setprio(0);

            // A-half1 into fresh frag
            bfrag ag[4][2];
#pragma unroll
            for (int mf = 0; mf < 4; ++mf)
#pragma unroll
                for (int ks = 0; ks < 2; ++ks)
                    ag[mf][ks] = *(const bfrag*)&lds[cur][0][(arow0 + 64 + mf * 16) * 64 + (((ks * 4 + lr16) ^ sw) * 8)];

            // blk2 (mh1,nh1) + blk3 (mh1,nh0)
            asm volatile("s_waitcnt lgkmcnt(0)" ::: "memory");
            __builtin_amdgcn_sched_barrier(0);
            __builtin_amdgcn_s_setprio(1);
#pragma unroll
            for (int mf = 0; mf < 4; ++mf)
#pragma unroll
                for (int nf = 0; nf < 2; ++nf)
#pragma unroll
                    for (int ks = 0; ks < 2; ++ks)
                        acc[4 + mf][2 + nf] = __builtin_amdgcn_mfma_f32_16x16x32_bf16(
                            ag[mf][ks], bB1[nf][ks], acc[4 + mf][2 + nf], 0, 0, 0);
#pragma unroll
            for (int mf = 0; mf < 4; ++mf)
#pragma unroll
                for (int nf = 0; nf < 2; ++nf)
#pragma unroll
                    for (int ks = 0; ks < 2; ++ks)
                        acc[4 + mf][nf] = __builtin_amdgcn_mfma_f32_16x16x32_bf16(
                            ag[mf][ks], bB0[nf][ks], acc[4 + mf][nf], 0, 0, 0);
            __builtin_amdgcn_s_setprio(0);
        } else {
            // ======== ODD waves: A-half1 first (mirrored) ========
            bfrag ag[4][2];
            // issue: bB1 (4), ag = A-half1 (8), bB0 (4)
#pragma unroll
            for (int nf = 0; nf < 2; ++nf)
#pragma unroll
                for (int ks = 0; ks < 2; ++ks)
                    bB1[nf][ks] = *(const bfrag*)&lds[cur][1][(brow0 + 32 + nf * 16) * 64 + (((ks * 4 + lr16) ^ sw) * 8)];
#pragma unroll
            for (int mf = 0; mf < 4; ++mf)
#pragma unroll
                for (int ks = 0; ks < 2; ++ks)
                    ag[mf][ks] = *(const bfrag*)&lds[cur][0][(arow0 + 64 + mf * 16) * 64 + (((ks * 4 + lr16) ^ sw) * 8)];
            asm volatile("" ::: "memory");
#pragma unroll
            for (int nf = 0; nf < 2; ++nf)
#pragma unroll
                for (int ks = 0; ks < 2; ++ks)
                    bB0[nf][ks] = *(const bfrag*)&lds[cur][1][(brow0 + nf * 16) * 64 + (((ks * 4 + lr16) ^ sw) * 8)];

            if (kt + 1 < NT) stage(kt + 1, cur ^ 1);

            // blk2 (mh1,nh1)
            asm volatile("s_waitcnt lgkmcnt(4)" ::: "memory");
            __builtin_amdgcn_sched_barrier(0);
            __builtin_amdgcn_s_setprio(1);
#pragma unroll
            for (int mf = 0; mf < 4; ++mf)
#pragma unroll
                for (int nf = 0; nf < 2; ++nf)
#pragma unroll
                    for (int ks = 0; ks < 2; ++ks)
                        acc[4 + mf][2 + nf] = __builtin_amdgcn_mfma_f32_16x16x32_bf16(
                            ag[mf][ks], bB1[nf][ks], acc[4 + mf][2 + nf], 0, 0, 0);
            __builtin_amdgcn_s_setprio(0);

            // blk3 (mh1,nh0)
            asm volatile("s_waitcnt lgkmcnt(0)" ::: "memory");
            __builtin_amdgcn_sched_barrier(0);
            __builtin_amdgcn_s_setprio(1);
#pragma unroll
            for (int mf = 0; mf < 4; ++mf)
#pragma unroll
                for (int nf = 0; nf < 2; ++nf)
#pragma unroll
                    for (int ks = 0; ks < 2; ++ks)
                        acc[4 + mf][nf] = __builtin_amdgcn_mfma_f32_16x16x32_bf16(
                            ag[mf][ks], bB0[nf][ks], acc[4 + mf][nf], 0, 0, 0);
            __builtin_amdgcn_s_setprio(0);

            // A-half0 into fresh frag
            bfrag af[4][2];
#pragma unroll
            for (int mf = 0; mf < 4; ++mf)
#pragma unroll
                for (int ks = 0; ks < 2; ++ks)
                    af[mf][ks] = *(const bfrag*)&lds[cur][0][(arow0 + mf * 16) * 64 + (((ks * 4 + lr16) ^ sw) * 8)];

            // blk0 (mh0,nh0) + blk1 (mh0,nh1)
            asm volatile("s_waitcnt lgkmcnt(0)" ::: "memory");
            __builtin_amdgcn_sched_barrier(0);
            __builtin_amdgcn_s_setprio(1);
#pragma unroll
            for (int mf = 0; mf < 4; ++mf)
#pragma unroll
                for (int nf = 0; nf < 2; ++nf)
#pragma unroll
                    for (int ks = 0; ks < 2; ++ks)
                        acc[mf][nf] = __builtin_amdgcn_mfma_f32_16x16x32_bf16(
                            af[mf][ks], bB0[nf][ks], acc[mf][nf], 0, 0, 0);
#pragma unroll
            for (int mf = 0; mf < 4; ++mf)
#pragma unroll
                for (int nf = 0; nf < 2; ++nf)
#pragma unroll
                    for (int ks = 0; ks < 2; ++ks)
                        acc[mf][2 + nf] = __builtin_amdgcn_mfma_f32_16x16x32_bf16(
                            af[mf][ks], bB1[nf][ks], acc[mf][2 + nf], 0, 0, 0);
            __builtin_amdgcn_s_setprio(0);
        }
        // no trailing barrier: next tile's top barrier provides it
    }

    // -------- epilogue --------
    const int rb = mt * 256 + wr * 128 + lr16 * 4;
    if (MODE == 0) {
        unsigned short* act = (unsigned short*)outv + (size_t)e * ROWS * I_;
#pragma unroll
        for (int nf = 0; nf < 2; ++nf) {
            const int jj = bt * 128 + wc * 32 + nf * 16 + l15;
            const float gb = bias[(size_t)e * N1 + 2 * jj];
            const float ub = bias[(size_t)e * N1 + 2 * jj + 1];
#pragma unroll
            for (int mf = 0; mf < 8; ++mf)
#pragma unroll
                for (int r = 0; r < 4; ++r) {
                    float g = acc[mf][nf][r] + gb;       // B rows 0-31  = gate
                    float u = acc[mf][2 + nf][r] + ub;   // B rows 32-63 = up (same jj)
                    g = fminf(g, 7.0f);
                    u = fminf(fmaxf(u, -7.0f), 7.0f);
                    const float glu = g / (1.0f + __expf(-1.702f * g));
                    const float av = (u + 1.0f) * glu;
                    act[(size_t)(rb + mf * 16 + r) * I_ + jj] = f2bf(av);
                }
        }
    } else {
        float* out = (float*)outv;
#pragma unroll
        for (int nf = 0; nf < 4; ++nf) {
            const int h = bt * 256 + wc * 64 + nf * 16 + l15;
            const float bb = bias[(size_t)e * H_ + h];
#pragma unroll
            for (int mf = 0; mf < 8; ++mf)
#pragma unroll
                for (int r = 0; r < 4; ++r) {
                    const int row = rb + mf * 16 + r;
                    out[((size_t)row * E_ + e) * H_ + h] = acc[mf][nf][r] + bb;
                }
        }
    }
}

// ---------------- launch ----------------

extern "C" void kernel_launch(void* const* d_in, const int* in_sizes, int n_in,
                              void* d_out, int out_size, void* d_ws, size_t ws_size,
                              hipStream_t stream) {
    const float* disp  = (const float*)d_in[0];
    const float* gup   = (const float*)d_in[1];
    const float* gub   = (const float*)d_in[2];
    const float* down  = (const float*)d_in[3];
    const float* dbias = (const float*)d_in[4];
    float* out = (float*)d_out;

    const size_t NEED = (size_t)512 << 20;
    if (ws_size < NEED) {
        hipMemsetAsync(d_out, 0, (size_t)out_size * sizeof(float), stream);
        return;
    }
    unsigned short* a_bf = (unsigned short*)d_ws;
    unsigned short* b1t  = (unsigned short*)((char*)d_ws + ((size_t)128 << 20));
    unsigned short* b2t  = b1t;  // reused after gemm1 (stream-ordered)
    unsigned short* actb = (unsigned short*)((char*)d_ws + ((size_t)384 << 20));

    convert_a<<<4096, 256, 0, stream>>>(disp, a_bf);
    convert_b1<<<dim3(E_, H_ / 64, N1 / 128), 256, 0, stream>>>(gup, b1t);
    gemm8p<0><<<2048, 512, 0, stream>>>(a_bf, b1t, gub, actb);
    convert_b2<<<dim3(E_, I_ / 64, H_ / 64), 256, 0, stream>>>(down, b2t);
    gemm8p<1><<<1024, 512, 0, stream>>>(actb, b2t, dbias, out);
}

// Round 12
// 2721.858 us; speedup vs baseline: 1.4629x; 1.4629x over previous
//
#include <hip/hip_runtime.h>
#include <stdint.h>

#define DEV __device__ __forceinline__

constexpr int E_ = 16, M_ = 128, H_ = 2048, I_ = 2048;
constexpr int X_ = 16;            // A*B = 2*8
constexpr int N1 = 2 * I_;        // 4096
constexpr int ROWS = X_ * M_;     // 2048 rows per expert

typedef short bfrag __attribute__((ext_vector_type(8)));   // 8 bf16 (4 VGPRs)
typedef float ffrag __attribute__((ext_vector_type(4)));   // MFMA C/D frag
typedef unsigned short us8 __attribute__((ext_vector_type(8)));

DEV unsigned short f2bf(float f) {
    union { float f; unsigned u; } v; v.f = f;
    unsigned u = v.u;
    u += 0x7fffu + ((u >> 16) & 1u);   // RNE
    return (unsigned short)(u >> 16);
}

DEV void gload16(const void* g, void* lds_wave_base) {
    __builtin_amdgcn_global_load_lds(
        (const __attribute__((address_space(1))) unsigned int*)g,
        (__attribute__((address_space(3))) unsigned int*)lds_wave_base,
        16, 0, 0);
}

DEV void block_bar() {
    asm volatile("" ::: "memory");
    __builtin_amdgcn_s_barrier();
    asm volatile("" ::: "memory");
}

// ---------------- converts ----------------

// dispatched (X,E,M,H) f32 -> a_bf (E, X*M, H) bf16  (token-major per expert)
__global__ __launch_bounds__(256) void convert_a(const float* __restrict__ in,
                                                 unsigned short* __restrict__ outb) {
    const int n4 = X_ * E_ * M_ * H_ / 4;
    int idx = blockIdx.x * 256 + threadIdx.x;
    int stride = gridDim.x * 256;
    for (int f = idx; f < n4; f += stride) {
        float4 v = ((const float4*)in)[f];
        ushort4 o;
        o.x = f2bf(v.x); o.y = f2bf(v.y); o.z = f2bf(v.z); o.w = f2bf(v.w);
        const int c = f & 511;          // float4 within row (H/4 = 512)
        const int row = f >> 9;         // (x,e,m) row
        const int m = row & 127, e = (row >> 7) & 15, x = row >> 11;
        ((ushort4*)outb)[((size_t)(e * ROWS + x * M_ + m) << 9) + c] = o;
    }
}

// gate_up (E,H,4096) fp32 -> b1t (E,4096,H) bf16, de-interleaved
__global__ __launch_bounds__(256) void convert_b1(const float* __restrict__ gup,
                                                  unsigned short* __restrict__ b1t) {
    const int e = blockIdx.x, h0 = blockIdx.y * 64, n0 = blockIdx.z * 128;
    __shared__ float tile[64][129];
    const float* src = gup + (size_t)e * H_ * N1;
    const int t = threadIdx.x;
#pragma unroll
    for (int i = 0; i < 8; ++i) {
        int idx = i * 1024 + t * 4;
        int r = idx >> 7, c = idx & 127;
        float4 v = *(const float4*)(src + (size_t)(h0 + r) * N1 + n0 + c);
        tile[r][c] = v.x; tile[r][c + 1] = v.y; tile[r][c + 2] = v.z; tile[r][c + 3] = v.w;
    }
    __syncthreads();
    const int p = t >> 2;
    const int hh = (t & 3) * 16;
    us8 g0, g1, u0, u1;
#pragma unroll
    for (int k = 0; k < 8; ++k) {
        g0[k] = f2bf(tile[hh + k][2 * p]);
        u0[k] = f2bf(tile[hh + k][2 * p + 1]);
        g1[k] = f2bf(tile[hh + 8 + k][2 * p]);
        u1[k] = f2bf(tile[hh + 8 + k][2 * p + 1]);
    }
    unsigned short* dg = b1t + ((size_t)e * N1 + (n0 >> 1) + p) * H_ + h0 + hh;
    unsigned short* du = b1t + ((size_t)e * N1 + I_ + (n0 >> 1) + p) * H_ + h0 + hh;
    *(us8*)dg = g0; *(us8*)(dg + 8) = g1;
    *(us8*)du = u0; *(us8*)(du + 8) = u1;
}

// down (E,I,H) fp32 -> b2t (E,H,I) bf16
__global__ __launch_bounds__(256) void convert_b2(const float* __restrict__ dwn,
                                                  unsigned short* __restrict__ b2t) {
    const int e = blockIdx.x, i0 = blockIdx.y * 64, h0 = blockIdx.z * 64;
    __shared__ float tile[64][65];
    const float* src = dwn + (size_t)e * I_ * H_;
    const int t = threadIdx.x;
#pragma unroll
    for (int it = 0; it < 4; ++it) {
        int idx = it * 1024 + t * 4;
        int r = idx >> 6, c = idx & 63;
        float4 v = *(const float4*)(src + (size_t)(i0 + r) * H_ + h0 + c);
        tile[r][c] = v.x; tile[r][c + 1] = v.y; tile[r][c + 2] = v.z; tile[r][c + 3] = v.w;
    }
    __syncthreads();
    const int hl = t >> 2, ii = (t & 3) * 16;
    us8 o0, o1;
#pragma unroll
    for (int k = 0; k < 8; ++k) {
        o0[k] = f2bf(tile[ii + k][hl]);
        o1[k] = f2bf(tile[ii + 8 + k][hl]);
    }
    unsigned short* d = b2t + ((size_t)e * H_ + h0 + hl) * I_ + i0 + ii;
    *(us8*)d = o0; *(us8*)(d + 8) = o1;
}

// ---- 256x256 8-wave, BK=64: B via LDS (staged), A DIRECT FROM GLOBAL ----
// MODE 0: gemm1 (gate_up + GLU epilogue); MODE 1: gemm2 (down proj + bias).
//
// Round-6's limiter: LDS pipe (192KB reads + 64KB writes ~ 2760 cyc/tile)
// serialized with MFMA (2483) because all waves' reads complete together.
// Fix: A-frags (4x-redundant in LDS) are read STRAIGHT FROM GLOBAL
// (16 rows x 64B contiguous per instr; A panel is L2-resident because the
// XCD swizzle puts all 16 bt-blocks of a panel on one XCD). LDS carries
// only B: ~1150 cyc/tile << MFMA floor -> MFMA-bound if overlapped.
// A loads for tile kt+1's first half are issued DURING kt (ping-pong regs),
// so blk0 has zero read latency at the tile top.
// Arch-VGPR budget (cap 128 w/ acc=128 AGPR): bB 32 + ag 32 + AFN 32 +
// addr ~25 = ~121. No spill expected (tripwire: WRITE_SIZE).
//
// Per tile kt: bar(publish buf[cur]) -> ds_read bB0(4),bB1(4) ->
//   stage B(kt+1)[vm4] -> A-loads ag(kt,mh1)[vm12] ->
//   lgkm(4): blk0 = AFC x bB0 -> lgkm(0): blk1 = AFC x bB1 ->
//   A-loads AFN(kt+1,mh0)[vm20] -> vmcnt(8) [drains stage+ag, keeps AFN] ->
//   blk2 = ag x bB1 -> blk3 = ag x bB0.
// Barrier safety: stage(kt) drained by kt-1's vmcnt(8); buf[cur^1]'s reads
// lgkm(0)-complete before kt's barrier -> stage(kt+1) WAR-safe.
template <int MODE>
__global__ __launch_bounds__(512, 2) void gemm8p(
    const unsigned short* __restrict__ A,   // (E,2048,2048) bf16
    const unsigned short* __restrict__ B,   // MODE0: (E,4096,2048); MODE1: (E,2048,2048)
    const float* __restrict__ bias,         // MODE0: (E,4096) interleaved; MODE1: (E,2048)
    void* __restrict__ outv)                // MODE0: act bf16 (E,2048,2048); MODE1: f32 (2048,16,2048)
{
    constexpr int LD = 2048;
    constexpr int NT = 2048 / 64;           // 32 K-tiles

    __shared__ unsigned short lds[2][256 * 64];   // [buf][row*64+k]  (B only, 64 KB)

    const int t = threadIdx.x, wave = t >> 6, lane = t & 63;
    const int wr = wave >> 2, wc = wave & 3;         // 2M x 4N

    // XCD-aware bijective swizzle (nwg % 8 == 0 both modes); with this map
    // all blocks of an expert land on one XCD -> A panels are L2-resident.
    int id = blockIdx.x;
    const int cpx = gridDim.x >> 3;
    id = (id & 7) * cpx + (id >> 3);
    int e, mt, bt;
    if (MODE == 0) { e = id >> 7; mt = (id >> 4) & 7; bt = id & 15; }
    else           { e = id >> 6; mt = (id >> 3) & 7; bt = id & 7; }

    const unsigned short* Aexp = A + ((size_t)e * ROWS + mt * 256) * LD;
    const unsigned short* Bexp = (MODE == 0)
        ? B + (size_t)e * N1 * LD
        : B + ((size_t)e * H_ + bt * 256) * LD;

    ffrag acc[8][4];
#pragma unroll
    for (int i = 0; i < 8; ++i)
#pragma unroll
        for (int j = 0; j < 4; ++j) acc[i][j] = ffrag{0.f, 0.f, 0.f, 0.f};

    const int rsub = lane >> 3;
    const int csw = ((lane & 7) ^ (lane >> 3)) * 8;  // inverse-swizzled k-chunk (elements)

    // B-only staging: 256x64 tile = 32 KB = 4 gload16/wave
    auto stage = [&](int kt, int b) {
        const int k0 = kt * 64;
#pragma unroll
        for (int i = 0; i < 4; ++i) {
            const int Rb = (wave * 4 + i) * 8;
            const int r = Rb + rsub;
            int grow;
            if (MODE == 0)
                grow = ((r >> 5) & 1) * I_ + bt * 128 + (r >> 6) * 32 + (r & 31);
            else
                grow = r;
            gload16(Bexp + (size_t)grow * LD + k0 + csw, (void*)&lds[b][Rb * 64]);
        }
    };

    const int l15 = lane & 15, lr16 = lane >> 4, sw = lane & 7;
    const int arow0 = wr * 128 + l15;       // A row base (global)
    const int brow0 = wc * 64 + l15;        // B row base (LDS)

    // A-frag global pointer for (row, k-chunk): 16 rows x 64B contiguous/instr
    const unsigned short* Arow = Aexp + (size_t)arow0 * LD + lr16 * 8;

    bfrag afA[4][2], afB[4][2];

    // -------- prologue --------
    stage(0, 0);
    // A mh0 frags for tile 0 (global, compiler-tracked vmcnt)
#pragma unroll
    for (int mf = 0; mf < 4; ++mf)
#pragma unroll
        for (int ks = 0; ks < 2; ++ks)
            afA[mf][ks] = *(const bfrag*)(Arow + (size_t)(mf * 16) * LD + ks * 32);
    asm volatile("s_waitcnt vmcnt(8)" ::: "memory");   // drain stage(0); AF0 stays
    __builtin_amdgcn_sched_barrier(0);

#define TILE_BODY(KT_, AFC, AFN)                                                 \
  {                                                                              \
    const int kt_ = (KT_);                                                       \
    const int cur_ = kt_ & 1;                                                    \
    const int k0_ = kt_ * 64;                                                    \
    block_bar();   /* publish buf[cur_]; stage(kt_) drained in kt_-1 */          \
    bfrag bB0[2][2], bB1[2][2], ag[4][2];                                        \
    _Pragma("unroll")                                                            \
    for (int nf = 0; nf < 2; ++nf)                                               \
        _Pragma("unroll")                                                        \
        for (int ks = 0; ks < 2; ++ks)                                           \
            bB0[nf][ks] = *(const bfrag*)&lds[cur_][(brow0 + nf * 16) * 64 + (((ks * 4 + lr16) ^ sw) * 8)]; \
    asm volatile("" ::: "memory");                                               \
    _Pragma("unroll")                                                            \
    for (int nf = 0; nf < 2; ++nf)                                               \
        _Pragma("unroll")                                                        \
        for (int ks = 0; ks < 2; ++ks)                                           \
            bB1[nf][ks] = *(const bfrag*)&lds[cur_][(brow0 + 32 + nf * 16) * 64 + (((ks * 4 + lr16) ^ sw) * 8)]; \
    if (kt_ + 1 < NT) stage(kt_ + 1, cur_ ^ 1);            /* vm +4 */           \
    /* A mh1 frags for THIS tile (global) -> vm +8 */                            \
    _Pragma("unroll")                                                            \
    for (int mf = 0; mf < 4; ++mf)                                               \
        _Pragma("unroll")                                                        \
        for (int ks = 0; ks < 2; ++ks)                                           \
            ag[mf][ks] = *(const bfrag*)(Arow + (size_t)(64 + mf * 16) * LD + k0_ + ks * 32); \
    /* blk0: AFC x bB0 */                                                        \
    asm volatile("s_waitcnt lgkmcnt(4)" ::: "memory");                           \
    __builtin_amdgcn_sched_barrier(0);                                           \
    __builtin_amdgcn_s_setprio(1);                                               \
    _Pragma("unroll")                                                            \
    for (int mf = 0; mf < 4; ++mf)                                               \
        _Pragma("unroll")                                                        \
        for (int nf = 0; nf < 2; ++nf)                                           \
            _Pragma("unroll")                                                    \
            for (int ks = 0; ks < 2; ++ks)                                       \
                acc[mf][nf] = __builtin_amdgcn_mfma_f32_16x16x32_bf16(           \
                    AFC[mf][ks], bB0[nf][ks], acc[mf][nf], 0, 0, 0);             \
    __builtin_amdgcn_s_setprio(0);                                               \
    /* blk1: AFC x bB1 */                                                        \
    asm volatile("s_waitcnt lgkmcnt(0)" ::: "memory");                           \
    __builtin_amdgcn_sched_barrier(0);                                           \
    __builtin_amdgcn_s_setprio(1);                                               \
    _Pragma("unroll")                                                            \
    for (int mf = 0; mf < 4; ++mf)                                               \
        _Pragma("unroll")                                                        \
        for (int nf = 0; nf < 2; ++nf)                                           \
            _Pragma("unroll")                                                    \
            for (int ks = 0; ks < 2; ++ks)                                       \
                acc[mf][2 + nf] = __builtin_amdgcn_mfma_f32_16x16x32_bf16(       \
                    AFC[mf][ks], bB1[nf][ks], acc[mf][2 + nf], 0, 0, 0);         \
    __builtin_amdgcn_s_setprio(0);                                               \
    /* A mh0 frags for NEXT tile (global) -> vm +8; AFC regs now dead */         \
    if (kt_ + 1 < NT) {                                                          \
        _Pragma("unroll")                                                        \
        for (int mf = 0; mf < 4; ++mf)                                           \
            _Pragma("unroll")                                                    \
            for (int ks = 0; ks < 2; ++ks)                                       \
                AFN[mf][ks] = *(const bfrag*)(Arow + (size_t)(mf * 16) * LD + k0_ + 64 + ks * 32); \
        asm volatile("s_waitcnt vmcnt(8)" ::: "memory"); /* drain stage+ag */    \
    } else {                                                                     \
        asm volatile("s_waitcnt vmcnt(0)" ::: "memory"); /* drain ag */          \
    }                                                                            \
    __builtin_amdgcn_sched_barrier(0);                                           \
    /* blk2: ag x bB1 ; blk3: ag x bB0 */                                        \
    __builtin_amdgcn_s_setprio(1);                                               \
    _Pragma("unroll")                                                            \
    for (int mf = 0; mf < 4; ++mf)                                               \
        _Pragma("unroll")                                                        \
        for (int nf = 0; nf < 2; ++nf)                                           \
            _Pragma("unroll")                                                    \
            for (int ks = 0; ks < 2; ++ks)                                       \
                acc[4 + mf][2 + nf] = __builtin_amdgcn_mfma_f32_16x16x32_bf16(   \
                    ag[mf][ks], bB1[nf][ks], acc[4 + mf][2 + nf], 0, 0, 0);      \
    _Pragma("unroll")                                                            \
    for (int mf = 0; mf < 4; ++mf)                                               \
        _Pragma("unroll")                                                        \
        for (int nf = 0; nf < 2; ++nf)                                           \
            _Pragma("unroll")                                                    \
            for (int ks = 0; ks < 2; ++ks)                                       \
                acc[4 + mf][nf] = __builtin_amdgcn_mfma_f32_16x16x32_bf16(       \
                    ag[mf][ks], bB0[nf][ks], acc[4 + mf][nf], 0, 0, 0);          \
    __builtin_amdgcn_s_setprio(0);                                               \
  }

    for (int kt = 0; kt < NT; kt += 2) {
        TILE_BODY(kt,     afA, afB);
        TILE_BODY(kt + 1, afB, afA);
    }
#undef TILE_BODY

    // -------- epilogue --------
    const int rb = mt * 256 + wr * 128 + lr16 * 4;
    if (MODE == 0) {
        unsigned short* act = (unsigned short*)outv + (size_t)e * ROWS * I_;
#pragma unroll
        for (int nf = 0; nf < 2; ++nf) {
            const int jj = bt * 128 + wc * 32 + nf * 16 + l15;
            const float gb = bias[(size_t)e * N1 + 2 * jj];
            const float ub = bias[(size_t)e * N1 + 2 * jj + 1];
#pragma unroll
            for (int mf = 0; mf < 8; ++mf)
#pragma unroll
                for (int r = 0; r < 4; ++r) {
                    float g = acc[mf][nf][r] + gb;       // B rows 0-31  = gate
                    float u = acc[mf][2 + nf][r] + ub;   // B rows 32-63 = up (same jj)
                    g = fminf(g, 7.0f);
                    u = fminf(fmaxf(u, -7.0f), 7.0f);
                    const float glu = g / (1.0f + __expf(-1.702f * g));
                    const float av = (u + 1.0f) * glu;
                    act[(size_t)(rb + mf * 16 + r) * I_ + jj] = f2bf(av);
                }
        }
    } else {
        float* out = (float*)outv;
#pragma unroll
        for (int nf = 0; nf < 4; ++nf) {
            const int h = bt * 256 + wc * 64 + nf * 16 + l15;
            const float bb = bias[(size_t)e * H_ + h];
#pragma unroll
            for (int mf = 0; mf < 8; ++mf)
#pragma unroll
                for (int r = 0; r < 4; ++r) {
                    const int row = rb + mf * 16 + r;
                    out[((size_t)row * E_ + e) * H_ + h] = acc[mf][nf][r] + bb;
                }
        }
    }
}

// ---------------- launch ----------------

extern "C" void kernel_launch(void* const* d_in, const int* in_sizes, int n_in,
                              void* d_out, int out_size, void* d_ws, size_t ws_size,
                              hipStream_t stream) {
    const float* disp  = (const float*)d_in[0];
    const float* gup   = (const float*)d_in[1];
    const float* gub   = (const float*)d_in[2];
    const float* down  = (const float*)d_in[3];
    const float* dbias = (const float*)d_in[4];
    float* out = (float*)d_out;

    const size_t NEED = (size_t)512 << 20;
    if (ws_size < NEED) {
        hipMemsetAsync(d_out, 0, (size_t)out_size * sizeof(float), stream);
        return;
    }
    unsigned short* a_bf = (unsigned short*)d_ws;
    unsigned short* b1t  = (unsigned short*)((char*)d_ws + ((size_t)128 << 20));
    unsigned short* b2t  = b1t;  // reused after gemm1 (stream-ordered)
    unsigned short* actb = (unsigned short*)((char*)d_ws + ((size_t)384 << 20));

    convert_a<<<4096, 256, 0, stream>>>(disp, a_bf);
    convert_b1<<<dim3(E_, H_ / 64, N1 / 128), 256, 0, stream>>>(gup, b1t);
    gemm8p<0><<<2048, 512, 0, stream>>>(a_bf, b1t, gub, actb);
    convert_b2<<<dim3(E_, I_ / 64, H_ / 64), 256, 0, stream>>>(down, b2t);
    gemm8p<1><<<1024, 512, 0, stream>>>(actb, b2t, dbias, out);
}

// Round 13
// 1102.305 us; speedup vs baseline: 3.6123x; 2.4692x over previous
//
#include <hip/hip_runtime.h>
#include <stdint.h>

#define DEV __device__ __forceinline__

constexpr int E_ = 16, M_ = 128, H_ = 2048, I_ = 2048;
constexpr int X_ = 16;            // A*B = 2*8
constexpr int N1 = 2 * I_;        // 4096
constexpr int ROWS = X_ * M_;     // 2048 rows per expert

typedef short bfrag __attribute__((ext_vector_type(8)));   // 8 bf16 (4 VGPRs)
typedef float ffrag __attribute__((ext_vector_type(4)));   // MFMA C/D frag
typedef unsigned short us8 __attribute__((ext_vector_type(8)));

DEV unsigned short f2bf(float f) {
    union { float f; unsigned u; } v; v.f = f;
    unsigned u = v.u;
    u += 0x7fffu + ((u >> 16) & 1u);   // RNE
    return (unsigned short)(u >> 16);
}

DEV void gload16(const void* g, void* lds_wave_base) {
    __builtin_amdgcn_global_load_lds(
        (const __attribute__((address_space(1))) unsigned int*)g,
        (__attribute__((address_space(3))) unsigned int*)lds_wave_base,
        16, 0, 0);
}

DEV void block_bar() {
    asm volatile("" ::: "memory");
    __builtin_amdgcn_s_barrier();
    asm volatile("" ::: "memory");
}

// ---------------- converts ----------------

// dispatched (X,E,M,H) f32 -> a_bf (E, X*M, H) bf16  (token-major per expert)
__global__ __launch_bounds__(256) void convert_a(const float* __restrict__ in,
                                                 unsigned short* __restrict__ outb) {
    const int n4 = X_ * E_ * M_ * H_ / 4;
    int idx = blockIdx.x * 256 + threadIdx.x;
    int stride = gridDim.x * 256;
    for (int f = idx; f < n4; f += stride) {
        float4 v = ((const float4*)in)[f];
        ushort4 o;
        o.x = f2bf(v.x); o.y = f2bf(v.y); o.z = f2bf(v.z); o.w = f2bf(v.w);
        const int c = f & 511;          // float4 within row (H/4 = 512)
        const int row = f >> 9;         // (x,e,m) row
        const int m = row & 127, e = (row >> 7) & 15, x = row >> 11;
        ((ushort4*)outb)[((size_t)(e * ROWS + x * M_ + m) << 9) + c] = o;
    }
}

// gate_up (E,H,4096) fp32 -> b1t (E,4096,H) bf16, de-interleaved.
// LDS tile stored as float2 (gate,up pairs): read = 16 b64 ops/thread
// (was 32 scalar b32 at the same 4-way bank class -> half the instrs).
__global__ __launch_bounds__(256) void convert_b1(const float* __restrict__ gup,
                                                  unsigned short* __restrict__ b1t) {
    const int e = blockIdx.x, h0 = blockIdx.y * 64, n0 = blockIdx.z * 128;
    __shared__ float2 tile2[64][64];   // [h-local][n-pair]
    const float* src = gup + (size_t)e * H_ * N1;
    const int t = threadIdx.x;
#pragma unroll
    for (int i = 0; i < 8; ++i) {
        int idx = i * 1024 + t * 4;
        int r = idx >> 7, c = idx & 127;
        float4 v = *(const float4*)(src + (size_t)(h0 + r) * N1 + n0 + c);
        *(float4*)&tile2[r][c >> 1] = v;   // c%4==0 -> 16B aligned
    }
    __syncthreads();
    const int p = t >> 2;          // local output n-row 0..63
    const int hh = (t & 3) * 16;   // 16 h's per thread
    us8 g0, g1, u0, u1;
#pragma unroll
    for (int k = 0; k < 8; ++k) {
        float2 a = tile2[hh + k][p];
        float2 b = tile2[hh + 8 + k][p];
        g0[k] = f2bf(a.x); u0[k] = f2bf(a.y);
        g1[k] = f2bf(b.x); u1[k] = f2bf(b.y);
    }
    unsigned short* dg = b1t + ((size_t)e * N1 + (n0 >> 1) + p) * H_ + h0 + hh;
    unsigned short* du = b1t + ((size_t)e * N1 + I_ + (n0 >> 1) + p) * H_ + h0 + hh;
    *(us8*)dg = g0; *(us8*)(dg + 8) = g1;
    *(us8*)du = u0; *(us8*)(du + 8) = u1;
}

// down (E,I,H) fp32 -> b2t (E,H,I) bf16
__global__ __launch_bounds__(256) void convert_b2(const float* __restrict__ dwn,
                                                  unsigned short* __restrict__ b2t) {
    const int e = blockIdx.x, i0 = blockIdx.y * 64, h0 = blockIdx.z * 64;
    __shared__ float tile[64][65];
    const float* src = dwn + (size_t)e * I_ * H_;
    const int t = threadIdx.x;
#pragma unroll
    for (int it = 0; it < 4; ++it) {
        int idx = it * 1024 + t * 4;
        int r = idx >> 6, c = idx & 63;
        float4 v = *(const float4*)(src + (size_t)(i0 + r) * H_ + h0 + c);
        tile[r][c] = v.x; tile[r][c + 1] = v.y; tile[r][c + 2] = v.z; tile[r][c + 3] = v.w;
    }
    __syncthreads();
    const int hl = t >> 2, ii = (t & 3) * 16;
    us8 o0, o1;
#pragma unroll
    for (int k = 0; k < 8; ++k) {
        o0[k] = f2bf(tile[ii + k][hl]);
        o1[k] = f2bf(tile[ii + 8 + k][hl]);
    }
    unsigned short* d = b2t + ((size_t)e * H_ + h0 + hl) * I_ + i0 + ii;
    *(us8*)d = o0; *(us8*)(d + 8) = o1;
}

// ---- 256x256 8-wave, BK=64, 2-buf, free-run GEMM (round-6 body + ag-split) ----
// MODE 0: gemm1 (gate_up + GLU epilogue); MODE 1: gemm2 (down proj + bias).
// Proven best structure (513us gemm1, 48% MfmaUtil, VGPR=128, no spill).
// Only change vs round 6: ag's lgkm wait is SPLIT (lgkm(4) -> 8 MFMA on
// ag[0..1] while ag[2..3] drains -> lgkm(0) -> rest). Identical read
// order/count and register liveness -> zero spill risk.
template <int MODE>
__global__ __launch_bounds__(512, 2) void gemm8p(
    const unsigned short* __restrict__ A,   // (E,2048,2048) bf16
    const unsigned short* __restrict__ B,   // MODE0: (E,4096,2048); MODE1: (E,2048,2048)
    const float* __restrict__ bias,         // MODE0: (E,4096) interleaved; MODE1: (E,2048)
    void* __restrict__ outv)                // MODE0: act bf16 (E,2048,2048); MODE1: f32 (2048,16,2048)
{
    constexpr int LD = 2048;
    constexpr int NT = 2048 / 64;           // 32 K-tiles

    __shared__ unsigned short lds[2][2][256 * 64];   // [buf][A/B][row*64+k]

    const int t = threadIdx.x, wave = t >> 6, lane = t & 63;
    const int wr = wave >> 2, wc = wave & 3;         // 2M x 4N

    // XCD-aware bijective swizzle (nwg % 8 == 0 for both modes)
    int id = blockIdx.x;
    const int cpx = gridDim.x >> 3;
    id = (id & 7) * cpx + (id >> 3);
    int e, mt, bt;
    if (MODE == 0) { e = id >> 7; mt = (id >> 4) & 7; bt = id & 15; }
    else           { e = id >> 6; mt = (id >> 3) & 7; bt = id & 7; }

    const unsigned short* Aexp = A + ((size_t)e * ROWS + mt * 256) * LD;
    const unsigned short* Bexp = (MODE == 0)
        ? B + (size_t)e * N1 * LD
        : B + ((size_t)e * H_ + bt * 256) * LD;

    ffrag acc[8][4];
#pragma unroll
    for (int i = 0; i < 8; ++i)
#pragma unroll
        for (int j = 0; j < 4; ++j) acc[i][j] = ffrag{0.f, 0.f, 0.f, 0.f};

    const int rsub = lane >> 3;
    const int csw = ((lane & 7) ^ (lane >> 3)) * 8;  // inverse-swizzled k-chunk (elements)

    auto stage = [&](int kt, int b) {
        const int k0 = kt * 64;
#pragma unroll
        for (int i = 0; i < 4; ++i) {
            const int Rb = (wave * 4 + i) * 8;
            const int r = Rb + rsub;
            gload16(Aexp + (size_t)r * LD + k0 + csw, (void*)&lds[b][0][Rb * 64]);
        }
#pragma unroll
        for (int i = 0; i < 4; ++i) {
            const int Rb = (wave * 4 + i) * 8;
            const int r = Rb + rsub;
            int grow;
            if (MODE == 0)
                grow = ((r >> 5) & 1) * I_ + bt * 128 + (r >> 6) * 32 + (r & 31);
            else
                grow = r;
            gload16(Bexp + (size_t)grow * LD + k0 + csw, (void*)&lds[b][1][Rb * 64]);
        }
    };

    stage(0, 0);

    const int l15 = lane & 15, lr16 = lane >> 4, sw = lane & 7;
    const int arow0 = wr * 128 + l15;       // A row base for this wave/lane
    const int brow0 = wc * 64 + l15;        // B row base

#pragma unroll 2
    for (int kt = 0; kt < NT; ++kt) {
        const int cur = kt & 1;

        // drain this tile's stage loads (issued one tile ago -> ~free)
        asm volatile("s_waitcnt vmcnt(0)" ::: "memory");
        __builtin_amdgcn_sched_barrier(0);
        block_bar();   // publish buf[cur]; old buffer's reads all retired

        bfrag bB0[2][2], bB1[2][2];
        bfrag af[4][2];

        // issue reads: B0 (4), A0 (8), B1 (4)  -> 16 outstanding
#pragma unroll
        for (int nf = 0; nf < 2; ++nf)
#pragma unroll
            for (int ks = 0; ks < 2; ++ks)
                bB0[nf][ks] = *(const bfrag*)&lds[cur][1][(brow0 + nf * 16) * 64 + (((ks * 4 + lr16) ^ sw) * 8)];
#pragma unroll
        for (int mf = 0; mf < 4; ++mf)
#pragma unroll
            for (int ks = 0; ks < 2; ++ks)
                af[mf][ks] = *(const bfrag*)&lds[cur][0][(arow0 + mf * 16) * 64 + (((ks * 4 + lr16) ^ sw) * 8)];
        asm volatile("" ::: "memory");   // pin FIFO order
#pragma unroll
        for (int nf = 0; nf < 2; ++nf)
#pragma unroll
            for (int ks = 0; ks < 2; ++ks)
                bB1[nf][ks] = *(const bfrag*)&lds[cur][1][(brow0 + 32 + nf * 16) * 64 + (((ks * 4 + lr16) ^ sw) * 8)];

        // prefetch next tile into the other buffer (safe: post-barrier)
        if (kt + 1 < NT) stage(kt + 1, cur ^ 1);

        // MFMA block0 (mh0,nh0): needs B0+A0 -> allow B1's 4 outstanding
        asm volatile("s_waitcnt lgkmcnt(4)" ::: "memory");
        __builtin_amdgcn_sched_barrier(0);
        __builtin_amdgcn_s_setprio(1);
#pragma unroll
        for (int mf = 0; mf < 4; ++mf)
#pragma unroll
            for (int nf = 0; nf < 2; ++nf)
#pragma unroll
                for (int ks = 0; ks < 2; ++ks)
                    acc[mf][nf] = __builtin_amdgcn_mfma_f32_16x16x32_bf16(
                        af[mf][ks], bB0[nf][ks], acc[mf][nf], 0, 0, 0);
        __builtin_amdgcn_s_setprio(0);

        // MFMA block1 (mh0,nh1)
        asm volatile("s_waitcnt lgkmcnt(0)" ::: "memory");
        __builtin_amdgcn_sched_barrier(0);
        __builtin_amdgcn_s_setprio(1);
#pragma unroll
        for (int mf = 0; mf < 4; ++mf)
#pragma unroll
            for (int nf = 0; nf < 2; ++nf)
#pragma unroll
                for (int ks = 0; ks < 2; ++ks)
                    acc[mf][2 + nf] = __builtin_amdgcn_mfma_f32_16x16x32_bf16(
                        af[mf][ks], bB1[nf][ks], acc[mf][2 + nf], 0, 0, 0);
        __builtin_amdgcn_s_setprio(0);

        // A1 reads into a fresh frag (af dead -> same budget as round 6)
        bfrag ag[4][2];
#pragma unroll
        for (int mf = 0; mf < 4; ++mf)
#pragma unroll
            for (int ks = 0; ks < 2; ++ks)
                ag[mf][ks] = *(const bfrag*)&lds[cur][0][(arow0 + 64 + mf * 16) * 64 + (((ks * 4 + lr16) ^ sw) * 8)];

        // blk2a: ag[0..1] x bB1 while ag[2..3]'s 4 reads drain (ag-split)
        asm volatile("s_waitcnt lgkmcnt(4)" ::: "memory");
        __builtin_amdgcn_sched_barrier(0);
        __builtin_amdgcn_s_setprio(1);
#pragma unroll
        for (int mf = 0; mf < 2; ++mf)
#pragma unroll
            for (int nf = 0; nf < 2; ++nf)
#pragma unroll
                for (int ks = 0; ks < 2; ++ks)
                    acc[4 + mf][2 + nf] = __builtin_amdgcn_mfma_f32_16x16x32_bf16(
                        ag[mf][ks], bB1[nf][ks], acc[4 + mf][2 + nf], 0, 0, 0);
        __builtin_amdgcn_s_setprio(0);

        // blk2b + blk3: remaining 24 MFMA
        asm volatile("s_waitcnt lgkmcnt(0)" ::: "memory");
        __builtin_amdgcn_sched_barrier(0);
        __builtin_amdgcn_s_setprio(1);
#pragma unroll
        for (int mf = 2; mf < 4; ++mf)
#pragma unroll
            for (int nf = 0; nf < 2; ++nf)
#pragma unroll
                for (int ks = 0; ks < 2; ++ks)
                    acc[4 + mf][2 + nf] = __builtin_amdgcn_mfma_f32_16x16x32_bf16(
                        ag[mf][ks], bB1[nf][ks], acc[4 + mf][2 + nf], 0, 0, 0);
#pragma unroll
        for (int mf = 0; mf < 4; ++mf)
#pragma unroll
            for (int nf = 0; nf < 2; ++nf)
#pragma unroll
                for (int ks = 0; ks < 2; ++ks)
                    acc[4 + mf][nf] = __builtin_amdgcn_mfma_f32_16x16x32_bf16(
                        ag[mf][ks], bB0[nf][ks], acc[4 + mf][nf], 0, 0, 0);
        __builtin_amdgcn_s_setprio(0);
        // no trailing barrier: next tile's top barrier provides it
    }

    // -------- epilogue --------
    const int rb = mt * 256 + wr * 128 + lr16 * 4;
    if (MODE == 0) {
        unsigned short* act = (unsigned short*)outv + (size_t)e * ROWS * I_;
#pragma unroll
        for (int nf = 0; nf < 2; ++nf) {
            const int jj = bt * 128 + wc * 32 + nf * 16 + l15;
            const float gb = bias[(size_t)e * N1 + 2 * jj];
            const float ub = bias[(size_t)e * N1 + 2 * jj + 1];
#pragma unroll
            for (int mf = 0; mf < 8; ++mf)
#pragma unroll
                for (int r = 0; r < 4; ++r) {
                    float g = acc[mf][nf][r] + gb;       // B rows 0-31  = gate
                    float u = acc[mf][2 + nf][r] + ub;   // B rows 32-63 = up (same jj)
                    g = fminf(g, 7.0f);
                    u = fminf(fmaxf(u, -7.0f), 7.0f);
                    const float glu = g / (1.0f + __expf(-1.702f * g));
                    const float av = (u + 1.0f) * glu;
                    act[(size_t)(rb + mf * 16 + r) * I_ + jj] = f2bf(av);
                }
        }
    } else {
        float* out = (float*)outv;
#pragma unroll
        for (int nf = 0; nf < 4; ++nf) {
            const int h = bt * 256 + wc * 64 + nf * 16 + l15;
            const float bb = bias[(size_t)e * H_ + h];
#pragma unroll
            for (int mf = 0; mf < 8; ++mf)
#pragma unroll
                for (int r = 0; r < 4; ++r) {
                    const int row = rb + mf * 16 + r;
                    out[((size_t)row * E_ + e) * H_ + h] = acc[mf][nf][r] + bb;
                }
        }
    }
}

// ---------------- launch ----------------

extern "C" void kernel_launch(void* const* d_in, const int* in_sizes, int n_in,
                              void* d_out, int out_size, void* d_ws, size_t ws_size,
                              hipStream_t stream) {
    const float* disp  = (const float*)d_in[0];
    const float* gup   = (const float*)d_in[1];
    const float* gub   = (const float*)d_in[2];
    const float* down  = (const float*)d_in[3];
    const float* dbias = (const float*)d_in[4];
    float* out = (float*)d_out;

    const size_t NEED = (size_t)512 << 20;
    if (ws_size < NEED) {
        hipMemsetAsync(d_out, 0, (size_t)out_size * sizeof(float), stream);
        return;
    }
    unsigned short* a_bf = (unsigned short*)d_ws;
    unsigned short* b1t  = (unsigned short*)((char*)d_ws + ((size_t)128 << 20));
    unsigned short* b2t  = b1t;  // reused after gemm1 (stream-ordered)
    unsigned short* actb = (unsigned short*)((char*)d_ws + ((size_t)384 << 20));

    convert_a<<<4096, 256, 0, stream>>>(disp, a_bf);
    convert_b1<<<dim3(E_, H_ / 64, N1 / 128), 256, 0, stream>>>(gup, b1t);
    gemm8p<0><<<2048, 512, 0, stream>>>(a_bf, b1t, gub, actb);
    convert_b2<<<dim3(E_, I_ / 64, H_ / 64), 256, 0, stream>>>(down, b2t);
    gemm8p<1><<<1024, 512, 0, stream>>>(actb, b2t, dbias, out);
}